// Round 2
// baseline (567.689 us; speedup 1.0000x reference)
//
#include <hip/hip_runtime.h>
#include <math.h>

#define DD 128
typedef unsigned int   u32;
typedef unsigned short u16;
typedef short bf16x8 __attribute__((ext_vector_type(8)));
typedef float f32x4  __attribute__((ext_vector_type(4)));

__device__ __forceinline__ float lo2f(u32 p){ return __uint_as_float(p << 16); }
__device__ __forceinline__ float hi2f(u32 p){ return __uint_as_float(p & 0xFFFF0000u); }
__device__ __forceinline__ u16 f2bf(float f){
    u32 u = __float_as_uint(f);
    return (u16)((u + 0x7fffu + ((u >> 16) & 1u)) >> 16);   // RNE
}

// ---------------- CSR build ----------------
__global__ void k_hist(const int* __restrict__ dst, int* __restrict__ deg, int E){
    int i = blockIdx.x*256 + threadIdx.x;
    if (i < E) atomicAdd(&deg[dst[i]], 1);
}

__global__ void k_chunksum(const int* __restrict__ deg, int* __restrict__ csum,
                           float* __restrict__ invdeg, int n){
    __shared__ int sdata[256];
    int t = threadIdx.x;
    int i0 = blockIdx.x*512 + t*2;
    int a = (i0     < n) ? deg[i0]   : 0;
    int b = (i0 + 1 < n) ? deg[i0+1] : 0;
    if (i0     < n) invdeg[i0]   = 1.0f / (float)max(a, 1);
    if (i0 + 1 < n) invdeg[i0+1] = 1.0f / (float)max(b, 1);
    sdata[t] = a + b; __syncthreads();
    for (int off = 128; off > 0; off >>= 1){
        if (t < off) sdata[t] += sdata[t+off];
        __syncthreads();
    }
    if (t == 0) csum[blockIdx.x] = sdata[0];
}

__global__ void k_scanchunks(int* __restrict__ csum, int nchunks,
                             int* __restrict__ row_ptr, int n){
    __shared__ int s[256];
    __shared__ int carry_sh;
    int t = threadIdx.x;
    if (t == 0) carry_sh = 0;
    __syncthreads();
    for (int base = 0; base < nchunks; base += 256){
        int i = base + t;
        int v = (i < nchunks) ? csum[i] : 0;
        s[t] = v;
        __syncthreads();
        for (int off = 1; off < 256; off <<= 1){
            int u = (t >= off) ? s[t-off] : 0;
            __syncthreads();
            s[t] += u;
            __syncthreads();
        }
        int carry = carry_sh;
        int excl  = carry + s[t] - v;
        if (i < nchunks) csum[i] = excl;
        int tot = s[255];
        __syncthreads();
        if (t == 0) carry_sh = carry + tot;
        __syncthreads();
    }
    if (t == 0) row_ptr[n] = carry_sh;
}

__global__ void k_scanwithin(const int* __restrict__ deg, const int* __restrict__ csum,
                             int* __restrict__ row_ptr, int* __restrict__ cursor, int n){
    __shared__ int s[256];
    int t = threadIdx.x;
    int i0 = blockIdx.x*512 + t*2;
    int a = (i0     < n) ? deg[i0]   : 0;
    int b = (i0 + 1 < n) ? deg[i0+1] : 0;
    int tsum = a + b;
    s[t] = tsum; __syncthreads();
    for (int off = 1; off < 256; off <<= 1){
        int v = (t >= off) ? s[t-off] : 0;
        __syncthreads();
        s[t] += v;
        __syncthreads();
    }
    int excl = s[t] - tsum + csum[blockIdx.x];
    if (i0     < n){ row_ptr[i0]   = excl;     cursor[i0]   = excl;     }
    if (i0 + 1 < n){ row_ptr[i0+1] = excl + a; cursor[i0+1] = excl + a; }
}

__global__ void k_fill(const int* __restrict__ src, const int* __restrict__ dst,
                       int* __restrict__ cursor, int* __restrict__ sorted_src, int E){
    int i = blockIdx.x*256 + threadIdx.x;
    if (i < E){
        int p = atomicAdd(&cursor[dst[i]], 1);
        sorted_src[p] = src[i];
    }
}

__global__ void k_w2b3(const float* __restrict__ w0, const float* __restrict__ w1,
                       const float* __restrict__ w2,
                       u16* __restrict__ o0, u16* __restrict__ o1, u16* __restrict__ o2,
                       int nw){
    int i = blockIdx.x*256 + threadIdx.x;
    if (i >= nw) return;
    const float* s = (blockIdx.y == 0) ? w0 : (blockIdx.y == 1) ? w1 : w2;
    u16*         o = (blockIdx.y == 0) ? o0 : (blockIdx.y == 1) ? o1 : o2;
    o[i] = f2bf(s[i]);
}

// ---------------- MFMA GEMM + fused pre/post transforms ----------------
// PRE : 0 none | 1 logmap0 row-scale | 2 l2norm row-scale
// POST: 0 none | 1 l2norm
// RS = output row stride in u16 (packed layouts)
template<int PRE, int POST>
__device__ __forceinline__ void gemm_body(const float* __restrict__ X, const u16* __restrict__ Wb,
                                          const float* __restrict__ bias, u16* __restrict__ Y,
                                          int RS, int n_rows, const float* __restrict__ cptr){
    int t = threadIdx.x;
    int wave = t >> 6, lane = t & 63;
    int q = lane >> 4, m = lane & 15;
    int rowbase = blockIdx.x*64 + wave*16;
    int gr = min(rowbase + m, n_rows - 1);

    float4 xv[8];
    const float4* xp = (const float4*)(X + (size_t)gr*DD);
    #pragma unroll
    for (int c = 0; c < 4; c++){
        xv[2*c]   = xp[c*8 + q*2];
        xv[2*c+1] = xp[c*8 + q*2 + 1];
    }

    float scale = 1.0f;
    if (PRE != 0){
        float ss = 0.f;
        #pragma unroll
        for (int i = 0; i < 8; i++)
            ss += xv[i].x*xv[i].x + xv[i].y*xv[i].y + xv[i].z*xv[i].z + xv[i].w*xv[i].w;
        ss += __shfl_xor(ss, 16, 64);
        ss += __shfl_xor(ss, 32, 64);
        float nrm = sqrtf(ss);
        if (PRE == 1){
            float c  = cptr[0];
            c = (c > 0.f && c < 1e30f) ? c : 1.0f;
            float sc = sqrtf(c);
            float n2 = fmaxf(nrm, 1e-10f);
            float a  = fminf(sc*n2, 0.99999994f);
            scale = (2.0f/sc) * atanhf(a) / n2;
        } else {
            scale = 1.0f / fmaxf(nrm, 1e-12f);
        }
    }

    bf16x8 af[4];
    #pragma unroll
    for (int c = 0; c < 4; c++){
        const float* xf = (const float*)&xv[2*c];
        #pragma unroll
        for (int j = 0; j < 8; j++) af[c][j] = (short)f2bf(xf[j]*scale);
    }

    f32x4 acc[8];
    #pragma unroll
    for (int tl = 0; tl < 8; tl++) acc[tl] = (f32x4){0.f,0.f,0.f,0.f};

    const u16* wb = Wb + (size_t)m*DD + q*8;
    #pragma unroll
    for (int c = 0; c < 4; c++){
        #pragma unroll
        for (int tl = 0; tl < 8; tl++){
            bf16x8 bfr = *(const bf16x8*)(wb + (size_t)tl*16*DD + c*32);
            acc[tl] = __builtin_amdgcn_mfma_f32_16x16x32_bf16(af[c], bfr, acc[tl], 0, 0, 0);
        }
    }

    #pragma unroll
    for (int tl = 0; tl < 8; tl++){
        float bv = bias[tl*16 + m];
        #pragma unroll
        for (int r = 0; r < 4; r++) acc[tl][r] += bv;
    }
    if (POST == 1){
        float ssr[4] = {0.f,0.f,0.f,0.f};
        #pragma unroll
        for (int tl = 0; tl < 8; tl++)
            #pragma unroll
            for (int r = 0; r < 4; r++) ssr[r] += acc[tl][r]*acc[tl][r];
        #pragma unroll
        for (int r = 0; r < 4; r++){
            float s = ssr[r];
            s += __shfl_xor(s, 1, 64);
            s += __shfl_xor(s, 2, 64);
            s += __shfl_xor(s, 4, 64);
            s += __shfl_xor(s, 8, 64);
            float sc = 1.0f / fmaxf(sqrtf(s), 1e-12f);
            #pragma unroll
            for (int tl = 0; tl < 8; tl++) acc[tl][r] *= sc;
        }
    }
    #pragma unroll
    for (int r = 0; r < 4; r++){
        int grow = rowbase + q*4 + r;
        if (grow < n_rows){
            #pragma unroll
            for (int tl = 0; tl < 8; tl++)
                Y[(size_t)grow*RS + tl*16 + m] = f2bf(acc[tl][r]);
        }
    }
}

// PREB: layer0 = 1 (logmap0 on ball input), later layers = 0 (identity shortcut:
// log_map(0, exp_map(0, v)) == v, so raw mean feeds the next GEMM directly).
// e path writes hEB cols 0-127, b path hEB cols 128-255, s path hS (l2norm idempotent).
template<int PREB>
__global__ __launch_bounds__(256, 4)
void k_gemm3(const float* __restrict__ Xe, const float* __restrict__ Xb, const float* __restrict__ Xs,
             const u16* __restrict__ We, const u16* __restrict__ Wh, const u16* __restrict__ Ws,
             const float* __restrict__ be, const float* __restrict__ bb, const float* __restrict__ bs,
             u16* __restrict__ hEB, u16* __restrict__ hS,
             int n_rows, const float* __restrict__ cptr){
    if (blockIdx.y == 0)      gemm_body<0,0>(Xe, We, be, hEB,       256, n_rows, cptr);
    else if (blockIdx.y == 1) gemm_body<PREB,0>(Xb, Wh, bb, hEB+128, 256, n_rows, cptr);
    else                      gemm_body<2,1>(Xs, Ws, bs, hS,        128, n_rows, cptr);
}

// ---------------- XCD-sharded tiled aggregation ----------------
// blockIdx % 8 -> XCD (round-robin dispatch). Each XCD owns one 128B column-chunk:
//  pass A: hEB (512B rows) = 4 chunks x 2 node-halves  -> per-XCD ws 3.2MB (< 4MiB L2)
//  pass B: hS  (256B rows) = 2 chunks x 4 node-quarters-> per-XCD ws 1.6MB
// Wave = 8 groups x 8 lanes; group walks edges stride-8, lane loads uint4 (one full
// cache line per edge-chunk). e path gets LeakyReLU; b,s write raw means.
__device__ __forceinline__ void acc8(float* a, uint4 p){
    a[0] += lo2f(p.x); a[1] += hi2f(p.x);
    a[2] += lo2f(p.y); a[3] += hi2f(p.y);
    a[4] += lo2f(p.z); a[5] += hi2f(p.z);
    a[6] += lo2f(p.w); a[7] += hi2f(p.w);
}

__global__ __launch_bounds__(256)
void k_aggT(const u32* __restrict__ hEB, const u32* __restrict__ hS,
            const int* __restrict__ row_ptr, const int* __restrict__ sorted_src,
            const float* __restrict__ invdeg,
            float* __restrict__ oE, float* __restrict__ oB, float* __restrict__ oS,
            int n_rows){
    int xcd = blockIdx.x & 7;
    int idx = blockIdx.x >> 3;

    const u32* table; int rs, coff, nodebase, hi, outcol0, path;
    {
        int hf  = xcd & 1;
        int loA = (int)(((long long)n_rows * hf) >> 1);
        int hiA = (int)(((long long)n_rows * (hf+1)) >> 1);
        int nbA = (hiA - loA + 15) >> 4;
        if (idx < nbA){
            int cA = xcd >> 1;                    // 0..3 over eb row
            table = hEB; rs = 128; coff = cA*32;  // u32 units: 512B row, 128B chunk
            nodebase = loA + idx*16; hi = hiA;
            path = cA >> 1; outcol0 = (cA & 1)*64;
        } else {
            int i2 = idx - nbA;
            int qd = xcd & 3;
            int loB = (int)(((long long)n_rows * qd) >> 2);
            int hiB = (int)(((long long)n_rows * (qd+1)) >> 2);
            int nbB = (hiB - loB + 15) >> 4;
            if (i2 >= nbB) return;
            int cS = xcd >> 2;                    // 0..1 over s row
            table = hS; rs = 64; coff = cS*32;
            nodebase = loB + i2*16; hi = hiB;
            path = 2; outcol0 = cS*64;
        }
    }
    float* dest = (path == 0) ? oE : (path == 1) ? oB : oS;
    bool leaky = (path == 0);

    int w = threadIdx.x >> 6, lane = threadIdx.x & 63;
    int g = lane >> 3, l8 = lane & 7;
    const u32* tbl = table + coff + l8*4;

    for (int k = 0; k < 4; k++){
        int v = nodebase + w*4 + k;
        if (v >= hi) break;
        int beg = row_ptr[v], end = row_ptr[v+1];
        float a[8];
        #pragma unroll
        for (int i = 0; i < 8; i++) a[i] = 0.f;

        int p = beg + g;
        for (; p + 8 < end; p += 16){            // 2 line-gathers in flight
            int i0 = sorted_src[p];
            int i1 = sorted_src[p+8];
            uint4 c0 = *(const uint4*)(tbl + (size_t)i0*rs);
            uint4 c1 = *(const uint4*)(tbl + (size_t)i1*rs);
            acc8(a, c0); acc8(a, c1);
        }
        if (p < end){
            int i0 = sorted_src[p];
            uint4 c0 = *(const uint4*)(tbl + (size_t)i0*rs);
            acc8(a, c0);
        }

        #pragma unroll
        for (int i = 0; i < 8; i++){
            a[i] += __shfl_xor(a[i], 8, 64);
            a[i] += __shfl_xor(a[i], 16, 64);
            a[i] += __shfl_xor(a[i], 32, 64);
        }
        if (g == 0){
            float inv = invdeg[v];
            float o[8];
            #pragma unroll
            for (int i = 0; i < 8; i++){
                float x = a[i]*inv;
                o[i] = leaky ? (x > 0.f ? x : 0.2f*x) : x;
            }
            float4* dp = (float4*)(dest + (size_t)v*DD + outcol0 + l8*8);
            dp[0] = make_float4(o[0],o[1],o[2],o[3]);
            dp[1] = make_float4(o[4],o[5],o[6],o[7]);
        }
    }
}

// ---------------- final-layer b/s epilogues (expmap0 / l2norm) ----------------
__global__ __launch_bounds__(256)
void k_final(const float* __restrict__ tb, const float* __restrict__ ts,
             float* __restrict__ ob, float* __restrict__ os,
             int n_rows, const float* __restrict__ cptr){
    int wid = (blockIdx.x*256 + threadIdx.x) >> 6;
    if (wid >= n_rows) return;
    int lane = threadIdx.x & 63;
    float2 vb = *(const float2*)(tb + (size_t)wid*DD + lane*2);
    float2 vs = *(const float2*)(ts + (size_t)wid*DD + lane*2);
    float ssb = vb.x*vb.x + vb.y*vb.y;
    float sss = vs.x*vs.x + vs.y*vs.y;
    #pragma unroll
    for (int m = 32; m > 0; m >>= 1){
        ssb += __shfl_xor(ssb, m, 64);
        sss += __shfl_xor(sss, m, 64);
    }
    float cc = cptr[0];
    cc = (cc > 0.f && cc < 1e30f) ? cc : 1.0f;
    float sc = sqrtf(cc);
    float nb = fmaxf(sqrtf(ssb), 1e-10f);
    float scb = tanhf(sc*nb*0.5f) / (sc*nb);
    float scs = 1.0f / fmaxf(sqrtf(sss), 1e-12f);
    *(float2*)(ob + (size_t)wid*DD + lane*2) = make_float2(vb.x*scb, vb.y*scb);
    *(float2*)(os + (size_t)wid*DD + lane*2) = make_float2(vs.x*scs, vs.y*scs);
}

extern "C" void kernel_launch(void* const* d_in, const int* in_sizes, int n_in,
                              void* d_out, int out_size, void* d_ws, size_t ws_size,
                              hipStream_t stream){
    const int*   src = (const int*)d_in[0];
    const int*   dst = (const int*)d_in[1];
    const float* emb_in[3] = {(const float*)d_in[2], (const float*)d_in[3], (const float*)d_in[4]};
    const float* W_in[3]   = {(const float*)d_in[5], (const float*)d_in[7], (const float*)d_in[9]};
    const float* b_in[3]   = {(const float*)d_in[6], (const float*)d_in[8], (const float*)d_in[10]};
    const float* b_c       = (const float*)d_in[11];

    const int E  = in_sizes[0];
    const int ND = in_sizes[2];
    const int N  = ND / DD;
    const int Lnum = in_sizes[5] / (DD*DD);
    const int nw = Lnum*DD*DD;
    const int nchunks = (N + 511) / 512;

    char* w = (char*)d_ws;
    auto alloc = [&](size_t bytes)->char*{
        char* p = w; w += (bytes + 255) & ~(size_t)255; return p;
    };
    u32*   hEB       = (u32*)  alloc((size_t)ND*4);     // [N][256 u16] e|b packed
    u32*   hS        = (u32*)  alloc((size_t)ND*2);     // [N][128 u16] s
    float* tb        = (float*)alloc((size_t)ND*4);     // final-layer raw means
    float* ts        = (float*)alloc((size_t)ND*4);
    u16*   Wb[3];
    for (int i = 0; i < 3; i++) Wb[i] = (u16*)alloc((size_t)nw*2);
    float* invdeg    = (float*)alloc((size_t)N*4);
    int*   deg       = (int*)  alloc((size_t)N*4);
    int*   row_ptr   = (int*)  alloc((size_t)(N+1)*4);
    int*   cursor    = (int*)  alloc((size_t)N*4);
    int*   csum      = (int*)  alloc((size_t)nchunks*4);
    int*   sorted_src= (int*)  alloc((size_t)E*4);
    (void)ws_size; (void)n_in; (void)out_size;

    float* out_e = (float*)d_out;
    float* out_b = out_e + ND;
    float* out_s = out_e + 2*ND;

    hipMemsetAsync(deg, 0, (size_t)N*4, stream);

    const int TB = 256;
    k_w2b3<<<dim3((nw+TB-1)/TB, 3), TB, 0, stream>>>(W_in[0], W_in[1], W_in[2],
                                                     Wb[0], Wb[1], Wb[2], nw);
    k_hist<<<(E+TB-1)/TB, TB, 0, stream>>>(dst, deg, E);
    k_chunksum<<<nchunks, 256, 0, stream>>>(deg, csum, invdeg, N);
    k_scanchunks<<<1, 256, 0, stream>>>(csum, nchunks, row_ptr, N);
    k_scanwithin<<<nchunks, 256, 0, stream>>>(deg, csum, row_ptr, cursor, N);
    k_fill<<<(E+TB-1)/TB, TB, 0, stream>>>(src, dst, cursor, sorted_src, E);

    const int gemmblocks = (N + 63) / 64;
    const int nbA = (((N+1)/2) + 15) / 16;
    const int nbB = (((N+3)/4) + 15) / 16;
    const int aggblocks = 8 * (nbA + nbB);
    const int finblocks = (N + 3) / 4;

    const float* se = emb_in[0];
    const float* sb = emb_in[1];
    const float* ss = emb_in[2];

    for (int l = 0; l < Lnum; l++){
        bool last = (l == Lnum - 1);
        if (l == 0)
            k_gemm3<1><<<dim3(gemmblocks, 3), 256, 0, stream>>>(
                se, sb, ss,
                Wb[0] + (size_t)l*DD*DD, Wb[1] + (size_t)l*DD*DD, Wb[2] + (size_t)l*DD*DD,
                b_in[0] + (size_t)l*DD,  b_in[1] + (size_t)l*DD,  b_in[2] + (size_t)l*DD,
                (u16*)hEB, (u16*)hS, N, b_c);
        else
            k_gemm3<0><<<dim3(gemmblocks, 3), 256, 0, stream>>>(
                se, sb, ss,
                Wb[0] + (size_t)l*DD*DD, Wb[1] + (size_t)l*DD*DD, Wb[2] + (size_t)l*DD*DD,
                b_in[0] + (size_t)l*DD,  b_in[1] + (size_t)l*DD,  b_in[2] + (size_t)l*DD,
                (u16*)hEB, (u16*)hS, N, b_c);

        float* dB = last ? tb : out_b;
        float* dS = last ? ts : out_s;
        k_aggT<<<aggblocks, 256, 0, stream>>>(hEB, hS, row_ptr, sorted_src, invdeg,
                                              out_e, dB, dS, N);
        if (last)
            k_final<<<finblocks, 256, 0, stream>>>(tb, ts, out_b, out_s, N, b_c);

        se = out_e; sb = out_b; ss = out_s;
    }
}